// Round 14
// baseline (101.149 us; speedup 1.0000x reference)
//
#include <hip/hip_runtime.h>
#include <cstddef>

// Block-cooperative MFMA MixModel, 32 rows/tile (R14 = in-register epilogue):
//   GEMM1 SWAPPED (R10/R13-verified): lane holds h[row=ln][4k] -> tanh_pade ->
//     cvt_pk -> ds_write_b64.
//   GEMM2 SWAPPED with 144-col padded layout (R11-verified data path):
//     internal col n = 8q+m: m<3 -> W2a[:,3q+m]; m==3 -> pad(0); m>=4 -> W2b[:,4q+m-4].
//     Lane (ln,lg) of tile g holds row ln, pair i=2g+(lg>>1):
//       lg even -> even triple {o00,o01,o02,0(pad)}; lg odd -> odd quad {o10..o13}.
//     9 tiles split 3/2/2/2 across waves; rb processed SERIALLY (acc2[3], not [2][3])
//     to keep peak VGPR < 128 (R11 spilled only because of (256,6)'s 85-reg cap).
//   EPILOGUE IN REGISTERS: no c2s buffer, no bar3, no w/18 divisions. Per-lane
//     parity-unified formula (even: acc[3]==0 kills the uC term; cue/c3 zero for odd):
//       res = acc0+cb + acc1*uA + (acc2+cuo)*uo + acc3*uC + c1*(uA*pa) + c2*(pb*up2)
//             + ue*(cue + c3*uo)
//   LDS 15872 B; 3 barriers/tile. Output = per-lane scalar stores.

typedef __attribute__((ext_vector_type(8))) __bf16 bf16x8;
typedef __attribute__((ext_vector_type(8))) short short8;
typedef __attribute__((ext_vector_type(4))) float f32x4;

__device__ __forceinline__ unsigned short f2bf(float f) {
    // manual RNE float->bf16 (init-time only)
    unsigned int u = __float_as_uint(f);
    unsigned int r = (u + 0x7FFFu + ((u >> 16) & 1u)) >> 16;
    return (unsigned short)r;
}

__device__ __forceinline__ unsigned int cvt_pk_bf16(float lo, float hi) {
    // gfx950 packed convert (R11/R13-verified)
    unsigned int r;
    asm("v_cvt_pk_bf16_f32 %0, %1, %2" : "=v"(r) : "v"(lo), "v"(hi));
    return r;
}

// --- mfma wrapper: tolerate either V8bf16 or V8i16 builtin signature ---
template <typename A>
__device__ __forceinline__ auto mfma_try(A a, A b, f32x4 c, int)
    -> decltype(__builtin_amdgcn_mfma_f32_16x16x32_bf16(a, b, c, 0, 0, 0)) {
    return __builtin_amdgcn_mfma_f32_16x16x32_bf16(a, b, c, 0, 0, 0);
}
template <typename A>
__device__ __forceinline__ f32x4 mfma_try(A a, A b, f32x4 c, long) {
    return __builtin_amdgcn_mfma_f32_16x16x32_bf16(
        __builtin_bit_cast(short8, a), __builtin_bit_cast(short8, b), c, 0, 0, 0);
}
__device__ __forceinline__ f32x4 mfma_bf16(short8 a, short8 b, f32x4 c) {
    return mfma_try(__builtin_bit_cast(bf16x8, a), __builtin_bit_cast(bf16x8, b), c, 0);
}

__device__ __forceinline__ float tanh_pade(float x) {
    // clamped Pade(3,2) (R11/R13-verified)
    const float t = fminf(fmaxf(x, -3.0f), 3.0f);
    const float s = t * t;
    return __fdividef(t * (27.0f + s), fmaf(9.0f, s, 27.0f));
}

__global__ __launch_bounds__(256, 4) void mixmodel_mfma14(
    const float* __restrict__ u,      // N*36
    const float* __restrict__ reg1,   // 6
    const float* __restrict__ reg2,   // 4
    const float* __restrict__ W1,     // 18*128
    const float* __restrict__ b1,     // 128
    const float* __restrict__ W2a,    // 128*54
    const float* __restrict__ b2a,    // 54
    const float* __restrict__ W2b,    // 128*72
    const float* __restrict__ b2b,    // 72
    float* __restrict__ out,          // N*36
    int N, int ntiles)
{
    __shared__ __align__(16) float          u_ext[32 * 40];   // 5120 B
    __shared__ __align__(16) unsigned short h_sh[32 * 136];   // 8704 B (verified layout)
    __shared__ __align__(16) unsigned short u_bf[32 * 32];    // 2048 B
    // total = 15872 B

    const int tid = threadIdx.x;
    const int wid = tid >> 6;
    const int l   = tid & 63;
    const int ln  = l & 15;
    const int lg  = l >> 4;
    const int nb  = wid * 32;        // GEMM1 column base

    reinterpret_cast<unsigned int*>(u_bf)[tid]       = 0u;
    reinterpret_cast<unsigned int*>(u_bf)[tid + 256] = 0u;
    __syncthreads();

    // ---- GEMM1 weights (swapped; R13-verified) ----
    short8 b1f[2];
    f32x4 bias1v[2];
#pragma unroll
    for (int t = 0; t < 2; ++t) {
        const int n = nb + t * 16 + ln;
        short8 v;
#pragma unroll
        for (int j = 0; j < 8; ++j) {
            const int k = lg * 8 + j;
            const float w = (k < 18) ? W1[k * 128 + n] : 0.0f;
            v[j] = (short)f2bf(w);
        }
        b1f[t] = v;
        bias1v[t] = *reinterpret_cast<const f32x4*>(&b1[nb + t * 16 + lg * 4]);
    }

    // ---- GEMM2 weights (swapped, 144-col; R11-verified): tiles 3/2/2/2 ----
    const int NT    = (wid == 0) ? 3 : 2;
    const int gbase = (wid == 0) ? 0 : 2 * wid + 1;  // {0,3,5,7} -> g sets {012,34,56,78}
    short8 b2f[3][4];
    f32x4 bias2v[3];
#pragma unroll
    for (int tl = 0; tl < 3; ++tl) {
        if (tl < NT) {
            const int g  = gbase + tl;
            const int nf = 16 * g + ln;          // A-operand row index (weights)
            const int q  = nf >> 3, m = nf & 7;
#pragma unroll
            for (int kk = 0; kk < 4; ++kk) {
                short8 w2;
#pragma unroll
                for (int j = 0; j < 8; ++j) {
                    const int k = kk * 32 + lg * 8 + j;
                    float w;
                    if (m < 3)       w = W2a[k * 54 + 3 * q + m];
                    else if (m == 3) w = 0.0f;
                    else             w = W2b[k * 72 + 4 * q + (m - 4)];
                    w2[j] = (short)f2bf(w);
                }
                b2f[tl][kk] = w2;
            }
            f32x4 bv;
#pragma unroll
            for (int r = 0; r < 4; ++r) {
                const int n  = 16 * g + 4 * lg + r;   // this lane's D-quad internal col
                const int qq = n >> 3, mm = n & 7;
                bv[r] = (mm < 3) ? b2a[3 * qq + mm]
                                 : (mm == 3 ? 0.0f : b2b[4 * qq + (mm - 4)]);
            }
            bias2v[tl] = bv;
        }
    }

    // ---- per-lane parity-selected regression coefficients ----
    const bool odd = (lg & 1) != 0;
    const float cb  = odd ? reg2[0] : reg1[0];
    const float cue = odd ? 0.0f    : reg1[1];
    const float cuo = odd ? reg2[1] : reg1[2];
    const float c1  = odd ? reg2[2] : reg1[3];
    const float c2c = odd ? reg2[3] : reg1[4];
    const float c3  = odd ? 0.0f    : reg1[5];

    const float4* ug = reinterpret_cast<const float4*>(u);
    const long fmax4 = (long)N * 9 - 1;
    const int gs = gridDim.x;

    // ---- staging maps (R8-verified) ----
    const int row0 = tid / 9,          c0 = tid - row0 * 9;
    const int row1 = (256 + tid) / 9,  c1s = (256 + tid) - row1 * 9;
    const int hrow = (tid - 192) >> 1, hside = tid & 1;

    float4 pf0, pf1; float2 pfh;
    {
        const int r0 = blockIdx.x * 32;
        long g0 = (long)r0 * 9 + tid; if (g0 > fmax4) g0 = fmax4;
        pf0 = ug[g0];
        if (tid < 32) {
            long g1 = (long)r0 * 9 + 256 + tid; if (g1 > fmax4) g1 = fmax4;
            pf1 = ug[g1];
        }
        if (tid >= 192) {
            int rr = r0 + hrow; if (rr > N - 1) rr = N - 1;
            pfh = *reinterpret_cast<const float2*>(u + (size_t)rr * 36 + (hside ? 0 : 34));
        }
    }

    for (int tile = blockIdx.x; tile < ntiles; tile += gs) {
        // ---- stage u_ext / u_bf (cvt_pk); prefetch next (R13-verified) ----
        {
            float* dst = &u_ext[row0 * 40 + 2 + c0 * 4];
            reinterpret_cast<float2*>(dst)[0] = make_float2(pf0.x, pf0.y);
            reinterpret_cast<float2*>(dst)[1] = make_float2(pf0.z, pf0.w);
            reinterpret_cast<unsigned int*>(u_bf)[row0 * 16 + c0] =
                cvt_pk_bf16(pf0.x, pf0.z);
            if (tid < 32) {
                float* dst1 = &u_ext[row1 * 40 + 2 + c1s * 4];
                reinterpret_cast<float2*>(dst1)[0] = make_float2(pf1.x, pf1.y);
                reinterpret_cast<float2*>(dst1)[1] = make_float2(pf1.z, pf1.w);
                reinterpret_cast<unsigned int*>(u_bf)[row1 * 16 + c1s] =
                    cvt_pk_bf16(pf1.x, pf1.z);
            }
            if (tid >= 192)
                *reinterpret_cast<float2*>(&u_ext[hrow * 40 + (hside ? 38 : 0)]) = pfh;

            if (tile + gs < ntiles) {
                const int r0n = (tile + gs) * 32;
                long g0 = (long)r0n * 9 + tid; if (g0 > fmax4) g0 = fmax4;
                pf0 = ug[g0];
                if (tid < 32) {
                    long g1 = (long)r0n * 9 + 256 + tid; if (g1 > fmax4) g1 = fmax4;
                    pf1 = ug[g1];
                }
                if (tid >= 192) {
                    int rr = r0n + hrow; if (rr > N - 1) rr = N - 1;
                    pfh = *reinterpret_cast<const float2*>(u + (size_t)rr * 36 + (hside ? 0 : 34));
                }
            }
        }
        __syncthreads();  // bar1: u ready

        // ---- GEMM1 SWAPPED (R13-verified): tanh_pade + cvt_pk -> ds_write_b64 ----
#pragma unroll
        for (int rb = 0; rb < 2; ++rb) {
            const short8 a1 = *reinterpret_cast<const short8*>(
                &u_bf[(rb * 16 + ln) * 32 + lg * 8]);
#pragma unroll
            for (int t = 0; t < 2; ++t) {
                const f32x4 h4 = mfma_bf16(b1f[t], a1, bias1v[t]);   // SWAPPED -> h^T
                const unsigned int p0 =
                    cvt_pk_bf16(tanh_pade(h4[0]), tanh_pade(h4[1]));
                const unsigned int p1 =
                    cvt_pk_bf16(tanh_pade(h4[2]), tanh_pade(h4[3]));
                *reinterpret_cast<uint2*>(
                    &h_sh[(rb * 16 + ln) * 136 + nb + t * 16 + lg * 4]) =
                    make_uint2(p0, p1);
            }
        }
        __syncthreads();  // bar2: h ready

        // ---- GEMM2 SWAPPED + in-register epilogue, rb serial ----
        const int r0 = tile * 32;
#pragma unroll
        for (int rb = 0; rb < 2; ++rb) {
            const int arow = rb * 16 + ln;

            // h fragments (B-operand; identical reads to R13)
            short8 a2f[4];
#pragma unroll
            for (int kk = 0; kk < 4; ++kk)
                a2f[kk] = *reinterpret_cast<const short8*>(
                    &h_sh[arow * 136 + kk * 32 + lg * 8]);

            f32x4 acc2[3];
#pragma unroll
            for (int tl = 0; tl < 3; ++tl)
                if (tl < NT) acc2[tl] = bias2v[tl];
#pragma unroll
            for (int kk = 0; kk < 4; ++kk)
#pragma unroll
                for (int tl = 0; tl < 3; ++tl)
                    if (tl < NT)
                        acc2[tl] = mfma_bf16(b2f[tl][kk], a2f[kk], acc2[tl]);  // SWAPPED

            // epilogue: lane owns (row=arow, pair i, parity odd)
            const int rg = r0 + arow;
#pragma unroll
            for (int tl = 0; tl < 3; ++tl) {
                if (tl < NT) {
                    const int i = 2 * (gbase + tl) + (lg >> 1);
                    const float* ub = &u_ext[arow * 40 + 2 * i];
                    const float2 v0 = *reinterpret_cast<const float2*>(ub);      // um2, uA
                    const float2 v1 = *reinterpret_cast<const float2*>(ub + 2);  // ue,  uo
                    const float2 v2 = *reinterpret_cast<const float2*>(ub + 4);  // up2, uC

                    const float um2 = v0.x, uA = v0.y;
                    const float ue  = v1.x, uo = v1.y;
                    const float up2 = v2.x, uC = v2.y;

                    const float pa = odd ? ue : um2;   // * uA
                    const float pb = odd ? ue : uA;    // * up2

                    float res = acc2[tl][0] + cb;
                    res = fmaf(acc2[tl][1], uA, res);
                    res = fmaf(acc2[tl][2] + cuo, uo, res);
                    res = fmaf(acc2[tl][3], uC, res);        // even lanes: acc[3]==0
                    res = fmaf(c1,  uA * pa,  res);
                    res = fmaf(c2c, pb * up2, res);
                    res = fmaf(ue,  fmaf(c3, uo, cue), res);

                    if (rg < N)
                        out[(size_t)rg * 36 + 2 * i + (odd ? 1 : 0)] = res;
                }
            }
        }
        __syncthreads();  // bar3: u_ext/u_bf/h_sh free for next staging
    }
}

extern "C" void kernel_launch(void* const* d_in, const int* in_sizes, int n_in,
                              void* d_out, int out_size, void* d_ws, size_t ws_size,
                              hipStream_t stream) {
    // d_in order: t, u, reg1, reg2, W1, b1, W2a, b2a, W2b, b2b
    const float* u    = (const float*)d_in[1];
    const float* reg1 = (const float*)d_in[2];
    const float* reg2 = (const float*)d_in[3];
    const float* W1   = (const float*)d_in[4];
    const float* b1   = (const float*)d_in[5];
    const float* W2a  = (const float*)d_in[6];
    const float* b2a  = (const float*)d_in[7];
    const float* W2b  = (const float*)d_in[8];
    const float* b2b  = (const float*)d_in[9];
    float* out = (float*)d_out;

    const int N = in_sizes[1] / 36;
    const int ntiles = (N + 31) / 32;
    int grid = ntiles < 1024 ? ntiles : 1024;
    if (grid < 1) grid = 1;
    mixmodel_mfma14<<<grid, 256, 0, stream>>>(u, reg1, reg2, W1, b1,
                                              W2a, b2a, W2b, b2b, out, N, ntiles);
}